// Round 9
// baseline (222.438 us; speedup 1.0000x reference)
//
#include <hip/hip_runtime.h>

typedef unsigned short u16;
typedef short short8 __attribute__((ext_vector_type(8)));
typedef float floatx4 __attribute__((ext_vector_type(4)));
typedef u16 u16x4 __attribute__((ext_vector_type(4)));
typedef u16 u16x8 __attribute__((ext_vector_type(8)));

#define DEVI __device__ __forceinline__

DEVI u16 f2bf(float x) {
    union { float f; unsigned u; } c; c.f = x;
    unsigned u = c.u;
    u += 0x7fffu + ((u >> 16) & 1u);   // RNE
    return (u16)(u >> 16);
}
DEVI u16 f2bf_fast(float x) {   // round-half-up, 2 ops — staging only
    union { float f; unsigned u; } c; c.f = x;
    return (u16)((c.u + 0x8000u) >> 16);
}
DEVI float bf2f(u16 h) {
    union { unsigned u; float f; } c; c.u = ((unsigned)h) << 16;
    return c.f;
}

DEVI void gload_lds16(const void* g, void* l) {
    auto gp = (const __attribute__((address_space(1))) unsigned*)(unsigned long long)g;
    auto lp = (__attribute__((address_space(3))) unsigned*)(unsigned)(unsigned long long)l;
    __builtin_amdgcn_global_load_lds(gp, lp, 16, 0, 0);
}

// ---------------- fused GroupNorm ----------------
__global__ __launch_bounds__(256) void gn_fused_kernel(const float* __restrict__ x,
                                                       const float* __restrict__ w,
                                                       const float* __restrict__ bb,
                                                       u16* __restrict__ h) {
    const int bg = blockIdx.x;           // b*32+g
    const int b = bg >> 5, g = bg & 31;
    const float* xg = x + (long long)bg * 16384;
    const int n0 = threadIdx.x * 4;

    float4 xv[16];
    float s = 0.f, s2 = 0.f;
    #pragma unroll
    for (int cc = 0; cc < 16; cc++) {
        xv[cc] = *(const float4*)&xg[cc * 1024 + n0];
        s  += xv[cc].x + xv[cc].y + xv[cc].z + xv[cc].w;
        s2 += xv[cc].x*xv[cc].x + xv[cc].y*xv[cc].y + xv[cc].z*xv[cc].z + xv[cc].w*xv[cc].w;
    }
    #pragma unroll
    for (int m = 1; m < 64; m <<= 1) { s += __shfl_xor(s, m, 64); s2 += __shfl_xor(s2, m, 64); }
    __shared__ float rs[4], rq[4];
    if ((threadIdx.x & 63) == 0) { rs[threadIdx.x >> 6] = s; rq[threadIdx.x >> 6] = s2; }
    __syncthreads();
    float mean = (rs[0] + rs[1] + rs[2] + rs[3]) * (1.f / 16384.f);
    float var  = (rq[0] + rq[1] + rq[2] + rq[3]) * (1.f / 16384.f) - mean * mean;
    float rstd = rsqrtf(var + 1e-5f);

    u16x8 o[4][2];
    #pragma unroll
    for (int cc = 0; cc < 16; cc++) {
        int c = g * 16 + cc;
        float sc = w[c] * rstd;
        float sh = bb[c] - mean * sc;
        o[0][cc >> 3][cc & 7] = f2bf(xv[cc].x * sc + sh);
        o[1][cc >> 3][cc & 7] = f2bf(xv[cc].y * sc + sh);
        o[2][cc >> 3][cc & 7] = f2bf(xv[cc].z * sc + sh);
        o[3][cc >> 3][cc & 7] = f2bf(xv[cc].w * sc + sh);
    }
    u16* hb = h + ((long long)b * 1024 + n0) * 512 + g * 16;
    #pragma unroll
    for (int k = 0; k < 4; k++) {
        *(u16x8*)&hb[(long long)k * 512]     = o[k][0];
        *(u16x8*)&hb[(long long)k * 512 + 8] = o[k][1];
    }
}

// ---------------- both weight conversions in one launch ----------------
__global__ __launch_bounds__(256) void wconv_kernel(const float* __restrict__ w1, u16* __restrict__ o1,
                                                    const float* __restrict__ w2, u16* __restrict__ o2) {
    int i = blockIdx.x * 256 + threadIdx.x;   // of 262144 float4 slots
    const float* src; u16* dst; int j;
    if (i < 196608) { src = w1; dst = o1; j = i; }
    else            { src = w2; dst = o2; j = i - 196608; }
    float4 v = *(const float4*)&src[j * 4];
    u16x4 p; p[0] = f2bf(v.x); p[1] = f2bf(v.y); p[2] = f2bf(v.z); p[3] = f2bf(v.w);
    *(u16x4*)&dst[j * 4] = p;
}

// ---------------- S = q k^T * scale, 64x64 tiles, + per-row expsum stats ----------------
// 4096 blocks: batch z on XCD z&7; per batch 16x16 tiles of 64.
__global__ __launch_bounds__(256, 6)
void gemm_s64_kernel(const u16* __restrict__ A, const u16* __restrict__ Bt,
                     u16* __restrict__ C, float* __restrict__ psum,
                     float scale, int lda, long long sAB, long long sC, int K) {
    const int lid  = blockIdx.x;
    const int xcd  = lid & 7;
    const int slot = lid >> 3;           // 0..511
    const int j    = slot >> 8;          // 0..1
    const int w    = slot & 255;         // 16x16
    const int bz   = xcd + 8 * j;
    const int bx   = w & 15, by = w >> 4;
    const int m0   = by * 64, n0 = bx * 64;
    A  += (long long)bz * sAB;
    Bt += (long long)bz * sAB;

    __shared__ __align__(16) u16 smem[8192];   // 16 KB: As[2][64][32] | Bs[2][64][32]
    u16* As = smem;
    u16* Bs = smem + 4096;

    const int t = threadIdx.x, lane = t & 63, wave = t >> 6;
    const int wm = wave >> 1, wn = wave & 1;
    const int quad = lane >> 4, lrow = lane & 15;

    floatx4 acc[2][2];
    #pragma unroll
    for (int i = 0; i < 2; i++)
        #pragma unroll
        for (int jj = 0; jj < 2; jj++)
            #pragma unroll
            for (int r = 0; r < 4; r++) acc[i][jj][r] = 0.f;

    const u16* Ag = A  + (long long)(m0 + (t >> 2)) * lda + (t & 3) * 8;
    const u16* Bg = Bt + (long long)(n0 + (t >> 2)) * lda + (t & 3) * 8;
    u16* Al = &As[t * 8];
    u16* Bl = &Bs[t * 8];

    for (int k0 = 0; k0 < K; k0 += 64) {
        gload_lds16(Ag + k0,      Al);
        gload_lds16(Ag + k0 + 32, Al + 2048);
        gload_lds16(Bg + k0,      Bl);
        gload_lds16(Bg + k0 + 32, Bl + 2048);
        __syncthreads();
        #pragma unroll
        for (int kk = 0; kk < 2; kk++) {
            short8 af[2], bfr[2];
            #pragma unroll
            for (int i = 0; i < 2; i++)
                af[i] = *(const short8*)&As[kk*2048 + (wm*32 + i*16 + lrow)*32 + quad*8];
            #pragma unroll
            for (int jj = 0; jj < 2; jj++)
                bfr[jj] = *(const short8*)&Bs[kk*2048 + (wn*32 + jj*16 + lrow)*32 + quad*8];
            #pragma unroll
            for (int i = 0; i < 2; i++)
                #pragma unroll
                for (int jj = 0; jj < 2; jj++)
                    acc[i][jj] = __builtin_amdgcn_mfma_f32_16x16x32_bf16(af[i], bfr[jj], acc[i][jj], 0, 0, 0);
        }
        __syncthreads();
    }

    // single-pass epilogue: stage 64x64 bf16, ST=72
    const int ST = 72;
    #pragma unroll
    for (int i = 0; i < 2; i++)
        #pragma unroll
        for (int jj = 0; jj < 2; jj++)
            #pragma unroll
            for (int r = 0; r < 4; r++)
                smem[(wm*32 + i*16 + quad*4 + r)*ST + wn*32 + jj*16 + lrow] =
                    f2bf(acc[i][jj][r] * scale);
    __syncthreads();
    const int rr = t >> 2, cc = (t & 3) * 16;
    u16x8 a0 = *(u16x8*)&smem[rr * ST + cc];
    u16x8 a1 = *(u16x8*)&smem[rr * ST + cc + 8];
    u16* Cp = C + (long long)bz * sC + (long long)(m0 + rr) * 1024 + n0 + cc;
    *(u16x8*)Cp = a0;
    *(u16x8*)(Cp + 8) = a1;
    // per-row partial sum(exp) over this 64-col key block
    float ls = 0.f;
    #pragma unroll
    for (int e = 0; e < 8; e++)
        ls += __expf(bf2f(a0[e])) + __expf(bf2f(a1[e]));
    ls += __shfl_xor(ls, 1, 4);
    ls += __shfl_xor(ls, 2, 4);
    if ((t & 3) == 0)
        psum[(((long long)bz * 16 + bx) << 10) + m0 + rr] = ls;
}

// ---------------- TN GEMM, 128x128 tile, BK=64 ----------------
// MODE 1: bf16 out, scaled ([m][n])
// MODE 2: bf16 transposed out C0[n][m] + bias[m]
// MODE 3: out-fused: Bt staged as exp(S); fp32 out = acc*invl[n] + bias[m] + res;
//         invl computed in-block from psum (aux), 16 key-blocks
// NX>0: 1D launch, decoded so batch z runs on XCD z&7.
template <int MODE, int NX, int NY>
__global__ __launch_bounds__(256, 3)
void gemm_bt_kernel(const u16* __restrict__ A, const u16* __restrict__ Bt,
                    void* __restrict__ C0,
                    const float* __restrict__ bias, const float* __restrict__ res,
                    const float* __restrict__ aux,
                    float scale, int lda, int ldb, int ldc,
                    long long sA, long long sB, long long sC, long long sR, int K) {
    int bx, by, bz;
    if (NX > 0) {
        const int lid  = blockIdx.x;
        const int xcd  = lid & 7;
        const int slot = lid >> 3;
        const int per  = NX * NY;
        const int j    = slot / per;
        const int w    = slot - j * per;
        bz = xcd + 8 * j;
        bx = w % NX;
        by = w / NX;
    } else {
        bx = blockIdx.x; by = blockIdx.y; bz = blockIdx.z;
    }
    const int t    = threadIdx.x;
    const int lane = t & 63;
    const int wave = t >> 6;
    const int m0   = by * 128;
    const int n0   = bx * 128;
    A  += (long long)bz * sA;
    Bt += (long long)bz * sB;

    __shared__ __align__(16) u16 smem[16384];   // 32 KB: A[2][128][32] | B[2][128][32]
    u16* As = smem;
    u16* Bs = smem + 8192;

    const int wm = wave >> 1, wn = wave & 1;
    const int quad = lane >> 4, lrow = lane & 15;

    floatx4 acc[4][4];
    #pragma unroll
    for (int i = 0; i < 4; i++)
        #pragma unroll
        for (int j = 0; j < 4; j++)
            #pragma unroll
            for (int r = 0; r < 4; r++) acc[i][j][r] = 0.f;

    const int rowA = t >> 2;
    const int kch  = (t & 3) * 8;
    const u16* Ag = A  + (long long)(m0 + rowA) * lda + kch;
    const u16* Bg = Bt + (long long)(n0 + rowA) * ldb + kch;
    u16* Al = &As[t * 8];
    u16* Bl = &Bs[t * 8];
    const long long a64 = (long long)64 * lda;
    const long long b64 = (long long)64 * ldb;
    const u16* Bg3 = Bt + (long long)n0 * ldb;   // MODE3 row base

    for (int k0 = 0; k0 < K; k0 += 64) {
        gload_lds16(Ag + k0,            Al);
        gload_lds16(Ag + k0 + a64,      Al + 2048);
        gload_lds16(Ag + k0 + 32,       Al + 4096);
        gload_lds16(Ag + k0 + 32 + a64, Al + 6144);
        if (MODE != 3) {
            gload_lds16(Bg + k0,            Bl);
            gload_lds16(Bg + k0 + b64,      Bl + 2048);
            gload_lds16(Bg + k0 + 32,       Bl + 4096);
            gload_lds16(Bg + k0 + 32 + b64, Bl + 6144);
        } else {
            #pragma unroll
            for (int q = 0; q < 4; q++) {
                const int row = ((q & 1) ? 64 : 0) + (t >> 2);
                const int kc  = (q >> 1) * 32 + (t & 3) * 8;
                u16x8 sv = *(const u16x8*)&Bg3[(long long)row * ldb + k0 + kc];
                u16x8 ev;
                #pragma unroll
                for (int e = 0; e < 8; e++)
                    ev[e] = f2bf_fast(__expf(bf2f(sv[e])));
                *(u16x8*)&Bs[q * 2048 + t * 8] = ev;
            }
        }
        __syncthreads();
        #pragma unroll
        for (int kk = 0; kk < 2; kk++) {
            short8 af[4], bfr[4];
            #pragma unroll
            for (int i = 0; i < 4; i++)
                af[i] = *(const short8*)&As[kk*4096 + (wm*64 + i*16 + lrow)*32 + quad*8];
            #pragma unroll
            for (int j = 0; j < 4; j++)
                bfr[j] = *(const short8*)&Bs[kk*4096 + (wn*64 + j*16 + lrow)*32 + quad*8];
            #pragma unroll
            for (int i = 0; i < 4; i++)
                #pragma unroll
                for (int j = 0; j < 4; j++)
                    acc[i][j] = __builtin_amdgcn_mfma_f32_16x16x32_bf16(af[i], bfr[j], acc[i][j], 0, 0, 0);
        }
        __syncthreads();
    }
    // smem free from here

    const int ST = 136;  // u16 row stride (272 B = 17*16)

    if (MODE == 1) {
        #pragma unroll
        for (int p = 0; p < 4; p++) {
            if (p) __syncthreads();
            if (wm == (p >> 1)) {
                #pragma unroll
                for (int ii = 0; ii < 2; ii++) {
                    const int i = (p & 1) * 2 + ii;
                    const int row = ii * 16 + quad * 4;
                    #pragma unroll
                    for (int j = 0; j < 4; j++) {
                        const int cB = wn * 64 + j * 16 + lrow;
                        #pragma unroll
                        for (int r = 0; r < 4; r++)
                            smem[(row + r) * ST + cB] = f2bf(acc[i][j][r] * scale);
                    }
                }
            }
            __syncthreads();
            const int rr = t >> 3, cc = (t & 7) * 16;
            u16x8 a0 = *(u16x8*)&smem[rr * ST + cc];
            u16x8 a1 = *(u16x8*)&smem[rr * ST + cc + 8];
            u16* Cp = (u16*)C0 + (long long)bz * sC + (long long)(m0 + p * 32 + rr) * ldc + n0 + cc;
            *(u16x8*)Cp = a0;
            *(u16x8*)(Cp + 8) = a1;
        }
    } else if (MODE == 2) {
        #pragma unroll
        for (int p = 0; p < 4; p++) {
            if (p) __syncthreads();
            if (wn == (p >> 1)) {
                #pragma unroll
                for (int jj = 0; jj < 2; jj++) {
                    const int j = (p & 1) * 2 + jj;
                    const int row = jj * 16 + lrow;
                    #pragma unroll
                    for (int i = 0; i < 4; i++) {
                        const int mmL = wm * 64 + i * 16 + quad * 4;
                        u16x4 pk;
                        #pragma unroll
                        for (int r = 0; r < 4; r++)
                            pk[r] = f2bf(acc[i][j][r] + bias[m0 + mmL + r]);
                        *(u16x4*)&smem[row * ST + mmL] = pk;
                    }
                }
            }
            __syncthreads();
            const int rr = t >> 3, cc = (t & 7) * 16;
            u16x8 a0 = *(u16x8*)&smem[rr * ST + cc];
            u16x8 a1 = *(u16x8*)&smem[rr * ST + cc + 8];
            u16* Cp = (u16*)C0 + (long long)(n0 + p * 32 + rr) * ldc + m0 + cc;
            *(u16x8*)Cp = a0;
            *(u16x8*)(Cp + 8) = a1;
        }
    } else {
        // MODE 3: fp32 out = acc*invl[col] + bias[row] + res; invl from psum in-block
        float* smf = (float*)smem;
        const int SF = 132;                 // smf uses floats 0..2111
        float* invsh = smf + 2176;          // 128 floats
        float* C = (float*)C0 + (long long)bz * sC;
        const float* rz = res + (long long)bz * sR;
        #pragma unroll
        for (int p = 0; p < 8; p++) {
            if (p) __syncthreads();
            if (wm == (p >> 2)) {
                const int i = p & 3;
                #pragma unroll
                for (int j = 0; j < 4; j++) {
                    const int cB = wn * 64 + j * 16 + lrow;
                    #pragma unroll
                    for (int r = 0; r < 4; r++)
                        smf[(quad * 4 + r) * SF + cB] = acc[i][j][r];
                }
            }
            if (p == 0 && t < 128) {
                float l = 0.f;
                #pragma unroll
                for (int kb = 0; kb < 16; kb++)
                    l += aux[(((long long)bz * 16 + kb) << 10) + n0 + t];
                invsh[t] = 1.f / l;
            }
            __syncthreads();
            const int rr = t >> 4, cc = (t & 15) * 8;
            const float bsv = bias[m0 + p * 16 + rr];
            float4 il0 = *(const float4*)&invsh[cc];
            float4 il1 = *(const float4*)&invsh[cc + 4];
            const long long gro = (long long)(m0 + p * 16 + rr) * ldc + n0 + cc;
            float4 rv0 = *(const float4*)&rz[gro];
            float4 rv1 = *(const float4*)&rz[gro + 4];
            float4 ov0, ov1;
            ov0.x = smf[rr*SF + cc + 0] * il0.x + bsv + rv0.x;
            ov0.y = smf[rr*SF + cc + 1] * il0.y + bsv + rv0.y;
            ov0.z = smf[rr*SF + cc + 2] * il0.z + bsv + rv0.z;
            ov0.w = smf[rr*SF + cc + 3] * il0.w + bsv + rv0.w;
            ov1.x = smf[rr*SF + cc + 4] * il1.x + bsv + rv1.x;
            ov1.y = smf[rr*SF + cc + 5] * il1.y + bsv + rv1.y;
            ov1.z = smf[rr*SF + cc + 6] * il1.z + bsv + rv1.z;
            ov1.w = smf[rr*SF + cc + 7] * il1.w + bsv + rv1.w;
            *(float4*)&C[gro]     = ov0;
            *(float4*)&C[gro + 4] = ov1;
        }
    }
}

extern "C" void kernel_launch(void* const* d_in, const int* in_sizes, int n_in,
                              void* d_out, int out_size, void* d_ws, size_t ws_size,
                              hipStream_t stream) {
    (void)in_sizes; (void)n_in; (void)out_size; (void)ws_size;
    const float* x     = (const float*)d_in[0];
    const float* gn_w  = (const float*)d_in[1];
    const float* gn_b  = (const float*)d_in[2];
    const float* qkv_w = (const float*)d_in[3];
    const float* qkv_b = (const float*)d_in[4];
    const float* out_w = (const float*)d_in[5];
    const float* out_b = (const float*)d_in[6];
    float* out = (float*)d_out;

    char* ws = (char*)d_ws;
    u16*  h_t   = (u16*)ws;  ws += (size_t)16*1024*512*2;    // 16 MB h[b][n][c]
    u16*  qkv_t = (u16*)ws;  ws += (size_t)16*1024*1536*2;   // 48 MB qkv[b*n][1536]
    u16*  vprm  = (u16*)ws;  ws += (size_t)512*16384*2;      // 16 MB V' = Wo V^T : [c_out][b*1024+n]
    u16*  S     = (u16*)ws;  ws += (size_t)16*1024*1024*2;   // 32 MB S[b][n][m] (bf16, scaled)
    u16*  wq    = (u16*)ws;  ws += (size_t)1536*512*2;
    u16*  wo    = (u16*)ws;  ws += (size_t)512*512*2;
    float* psum = (float*)ws; ws += (size_t)16*16*1024*4;    // partial sum(exp) per 64-key block

    wconv_kernel<<<1024, 256, 0, stream>>>(qkv_w, wq, out_w, wo);
    gn_fused_kernel<<<512, 256, 0, stream>>>(x, gn_w, gn_b, h_t);

    // QKV: M=1536, Nn=16384, K=512 ; all transposed -> qkv_t[bn][1536] + bias
    gemm_bt_kernel<2, 0, 0><<<dim3(128, 12, 1), 256, 0, stream>>>(
        wq, h_t, qkv_t, qkv_b, nullptr, nullptr, 1.0f,
        512, 512, 1536, 0, 0, 0, 0, 512);

    // V' = Wo @ V^T : M=512(c_out), Nn=16384(bn), K=512(c_in)
    gemm_bt_kernel<1, 0, 0><<<dim3(128, 4, 1), 256, 0, stream>>>(
        wo, qkv_t + 1024, vprm, nullptr, nullptr, nullptr, 1.0f,
        512, 1536, 16384, 0, 0, 0, 0, 512);

    // S = q k^T * scale : 64x64 tiles, 4096 blocks, XCD-affine, + expsum stats
    gemm_s64_kernel<<<4096, 256, 0, stream>>>(
        qkv_t, qkv_t + 512, S, psum, 0.044194173824159216f,
        1536, (long long)1024*1536, (long long)1024*1024, 512);

    // out = vprm ⊗ exp(S) * invl + out_b + x : M=512, Nn=1024(n), K=1024(m) ; XCD-affine
    gemm_bt_kernel<3, 8, 4><<<512, 256, 0, stream>>>(
        vprm, S, out, out_b, x, psum, 1.0f,
        16384, 1024, 1024,
        1024, (long long)1024*1024, (long long)512*1024, (long long)512*1024, 1024);
}